// Round 1
// baseline (661.234 us; speedup 1.0000x reference)
//
#include <hip/hip_runtime.h>

typedef float  f32x4  __attribute__((ext_vector_type(4)));
typedef short  short8 __attribute__((ext_vector_type(8)));

#define LOG2E 1.4426950408889634f
#define NPIX 4096
#define CCH  512
#define DQK  64

__device__ __forceinline__ ushort f2b(float f) {
  union { float f; unsigned u; } v; v.f = f;
  unsigned r = v.u + 0x7fffu + ((v.u >> 16) & 1u);
  return (ushort)(r >> 16);
}

// x: [B][C][N] f32  ->  Xt: [B][N][C] bf16  (tiled transpose via LDS)
__global__ __launch_bounds__(256) void k_cast_x(const float* __restrict__ x,
                                                ushort* __restrict__ Xt) {
  __shared__ float tile[32][33];
  const int b = blockIdx.z;
  const int n0 = blockIdx.x * 32, c0 = blockIdx.y * 32;
  const int t = threadIdx.x;
  {
    int cc = t >> 3, nn = (t & 7) * 4;
    const float4 v = *(const float4*)&x[((size_t)b * CCH + c0 + cc) * NPIX + n0 + nn];
    tile[cc][nn] = v.x; tile[cc][nn + 1] = v.y; tile[cc][nn + 2] = v.z; tile[cc][nn + 3] = v.w;
  }
  __syncthreads();
  {
    int nr = t >> 3, c4 = (t & 7) * 4;
    ushort4 o;
    o.x = f2b(tile[c4 + 0][nr]); o.y = f2b(tile[c4 + 1][nr]);
    o.z = f2b(tile[c4 + 2][nr]); o.w = f2b(tile[c4 + 3][nr]);
    *(ushort4*)&Xt[((size_t)b * NPIX + n0 + nr) * CCH + c0 + c4] = o;
  }
}

// pack wq(64x512), wk(64x512), wv(512x512) -> Wb[640][512] bf16
__global__ __launch_bounds__(256) void k_cast_w(const float* __restrict__ wq,
                                                const float* __restrict__ wk,
                                                const float* __restrict__ wv,
                                                ushort* __restrict__ Wb) {
  int i = blockIdx.x * 256 + threadIdx.x;     // 81920 threads, 4 elems each
  int idx = i * 4;
  int j = idx >> 9, c = idx & 511;
  const float* src = (j < 64) ? &wq[(size_t)j * 512]
                   : (j < 128) ? &wk[(size_t)(j - 64) * 512]
                               : &wv[(size_t)(j - 128) * 512];
  float4 v = *(const float4*)&src[c];
  ushort4 o; o.x = f2b(v.x); o.y = f2b(v.y); o.z = f2b(v.z); o.w = f2b(v.w);
  *(ushort4*)&Wb[idx] = o;
}

// QKV projection GEMM: out[j,n] = sum_c Wb[j,c]*Xt[n,c] + bias[j]
// Q: [B][N][64], K: [B][N][64], V: [B][C][N]  (all bf16)
__global__ __launch_bounds__(256) void k_proj(const ushort* __restrict__ Xt,
                                              const ushort* __restrict__ Wb,
                                              const float* __restrict__ bq,
                                              const float* __restrict__ bk,
                                              const float* __restrict__ bv,
                                              ushort* __restrict__ Q,
                                              ushort* __restrict__ K,
                                              ushort* __restrict__ V) {
  __shared__ ushort Wl[64][72];
  __shared__ ushort Xl[64][72];
  const int b = blockIdx.z;
  const int n0 = blockIdx.x * 64;
  const int j0 = blockIdx.y * 64;
  const int t = threadIdx.x;
  const int w = t >> 6, l = t & 63;
  const int lr = l & 15, lq = l >> 4;
  const int wj = (w >> 1) * 32, wn = (w & 1) * 32;

  f32x4 acc[2][2];
#pragma unroll
  for (int a = 0; a < 2; ++a)
#pragma unroll
    for (int c = 0; c < 2; ++c) acc[a][c] = f32x4{0.f, 0.f, 0.f, 0.f};

  const int srow = t >> 2, sch = t & 3;
  for (int k0 = 0; k0 < 512; k0 += 64) {
    *(uint4*)&Wl[srow][sch * 8]       = *(const uint4*)&Wb[(size_t)(j0 + srow) * 512 + k0 + sch * 8];
    *(uint4*)&Wl[srow][(sch + 4) * 8] = *(const uint4*)&Wb[(size_t)(j0 + srow) * 512 + k0 + (sch + 4) * 8];
    *(uint4*)&Xl[srow][sch * 8]       = *(const uint4*)&Xt[((size_t)b * NPIX + n0 + srow) * 512 + k0 + sch * 8];
    *(uint4*)&Xl[srow][(sch + 4) * 8] = *(const uint4*)&Xt[((size_t)b * NPIX + n0 + srow) * 512 + k0 + (sch + 4) * 8];
    __syncthreads();
#pragma unroll
    for (int kt = 0; kt < 2; ++kt) {
      short8 af[2], bf[2];
#pragma unroll
      for (int jt = 0; jt < 2; ++jt)
        af[jt] = *(const short8*)&Wl[wj + jt * 16 + lr][kt * 32 + lq * 8];
#pragma unroll
      for (int nt = 0; nt < 2; ++nt)
        bf[nt] = *(const short8*)&Xl[wn + nt * 16 + lr][kt * 32 + lq * 8];
#pragma unroll
      for (int jt = 0; jt < 2; ++jt)
#pragma unroll
        for (int nt = 0; nt < 2; ++nt)
          acc[jt][nt] = __builtin_amdgcn_mfma_f32_16x16x32_bf16(af[jt], bf[nt], acc[jt][nt], 0, 0, 0);
    }
    __syncthreads();
  }

#pragma unroll
  for (int jt = 0; jt < 2; ++jt) {
    const int jb = j0 + wj + jt * 16;        // 16-row tile entirely within Q, K, or V
#pragma unroll
    for (int nt = 0; nt < 2; ++nt) {
      const int n = n0 + wn + nt * 16 + lr;
      const size_t nrow = (size_t)b * NPIX + n;
      if (jb < 64) {
        ushort4 o;
        o.x = f2b(acc[jt][nt][0] + bq[jb + lq * 4 + 0]);
        o.y = f2b(acc[jt][nt][1] + bq[jb + lq * 4 + 1]);
        o.z = f2b(acc[jt][nt][2] + bq[jb + lq * 4 + 2]);
        o.w = f2b(acc[jt][nt][3] + bq[jb + lq * 4 + 3]);
        *(ushort4*)&Q[nrow * DQK + jb + lq * 4] = o;
      } else if (jb < 128) {
        ushort4 o;
        o.x = f2b(acc[jt][nt][0] + bk[jb - 64 + lq * 4 + 0]);
        o.y = f2b(acc[jt][nt][1] + bk[jb - 64 + lq * 4 + 1]);
        o.z = f2b(acc[jt][nt][2] + bk[jb - 64 + lq * 4 + 2]);
        o.w = f2b(acc[jt][nt][3] + bk[jb - 64 + lq * 4 + 3]);
        *(ushort4*)&K[nrow * DQK + jb - 64 + lq * 4] = o;
      } else {
#pragma unroll
        for (int r = 0; r < 4; ++r) {
          int cch = jb - 128 + lq * 4 + r;
          V[((size_t)b * CCH + cch) * NPIX + n] = f2b(acc[jt][nt][r] + bv[cch]);
        }
      }
    }
  }
}

// flash attention: 4 waves x 16 queries, KBLK=32, full 512-ch accumulator/wave
__global__ __launch_bounds__(256) void k_attn(const ushort* __restrict__ Qb,
                                              const ushort* __restrict__ Kb,
                                              const ushort* __restrict__ Vb,
                                              const float* __restrict__ x,
                                              const float* __restrict__ gamma,
                                              float* __restrict__ out) {
  __shared__ ushort Klds[32][72];
  __shared__ ushort Vlds[512][40];
  __shared__ ushort Plds[4][16][40];

  const int b = blockIdx.y;
  const int q0 = blockIdx.x * 64;
  const int t = threadIdx.x;
  const int w = t >> 6, l = t & 63;
  const int lr = l & 15, lq = l >> 4;
  const int qw = q0 + w * 16;

  short8 qf[2];
#pragma unroll
  for (int kt = 0; kt < 2; ++kt)
    qf[kt] = *(const short8*)&Qb[((size_t)b * NPIX + qw + lr) * DQK + kt * 32 + lq * 8];

  f32x4 acc[32];
#pragma unroll
  for (int i = 0; i < 32; ++i) acc[i] = f32x4{0.f, 0.f, 0.f, 0.f};
  float M[4], L[4];
#pragma unroll
  for (int r = 0; r < 4; ++r) { M[r] = -1e30f; L[r] = 0.f; }

  const int krow = t >> 3, kch = t & 7;       // K stage: 32 rows x 8 chunks
  const int vch = t & 3, vrb = t >> 2;        // V stage: 512 rows x 4 chunks, 8 rows/thread

  for (int m0 = 0; m0 < NPIX; m0 += 32) {
    *(uint4*)&Klds[krow][kch * 8] =
        *(const uint4*)&Kb[((size_t)b * NPIX + m0 + krow) * DQK + kch * 8];
#pragma unroll
    for (int i = 0; i < 8; ++i) {
      int c = vrb + i * 64;
      *(uint4*)&Vlds[c][vch * 8] =
          *(const uint4*)&Vb[((size_t)b * CCH + c) * NPIX + m0 + vch * 8];
    }
    __syncthreads();

    // S = Q K^T  (2 m-tiles of 16 keys)
    f32x4 s[2];
#pragma unroll
    for (int mt = 0; mt < 2; ++mt) {
      f32x4 a = f32x4{0.f, 0.f, 0.f, 0.f};
#pragma unroll
      for (int kt = 0; kt < 2; ++kt) {
        short8 kf = *(const short8*)&Klds[mt * 16 + lr][kt * 32 + lq * 8];
        a = __builtin_amdgcn_mfma_f32_16x16x32_bf16(qf[kt], kf, a, 0, 0, 0);
      }
      s[mt] = a;
    }

    // online softmax (rows = q, cols = m across lanes 0..15)
    float rm[4];
#pragma unroll
    for (int r = 0; r < 4; ++r) rm[r] = fmaxf(s[0][r], s[1][r]);
#pragma unroll
    for (int mask = 1; mask < 16; mask <<= 1)
#pragma unroll
      for (int r = 0; r < 4; ++r) rm[r] = fmaxf(rm[r], __shfl_xor(rm[r], mask));

    bool ok = true;
#pragma unroll
    for (int r = 0; r < 4; ++r) ok = ok && (rm[r] <= M[r] + 8.f);
    if (!__all(ok)) {
#pragma unroll
      for (int r = 0; r < 4; ++r) {
        float nm = fmaxf(M[r], rm[r]);
        float sc = exp2f((M[r] - nm) * LOG2E);
        L[r] *= sc;
        M[r] = nm;
#pragma unroll
        for (int ct = 0; ct < 32; ++ct) acc[ct][r] *= sc;
      }
    }

    float ps[4] = {0.f, 0.f, 0.f, 0.f};
    ushort pb[2][4];
#pragma unroll
    for (int mt = 0; mt < 2; ++mt)
#pragma unroll
      for (int r = 0; r < 4; ++r) {
        float p = exp2f((s[mt][r] - M[r]) * LOG2E);
        ps[r] += p;
        pb[mt][r] = f2b(p);
      }
#pragma unroll
    for (int mask = 1; mask < 16; mask <<= 1)
#pragma unroll
      for (int r = 0; r < 4; ++r) ps[r] += __shfl_xor(ps[r], mask);
#pragma unroll
    for (int r = 0; r < 4; ++r) L[r] += ps[r];

    // P (D-layout) -> LDS -> A-fragment
#pragma unroll
    for (int mt = 0; mt < 2; ++mt)
#pragma unroll
      for (int r = 0; r < 4; ++r)
        Plds[w][lq * 4 + r][mt * 16 + lr] = pb[mt][r];
    short8 pf = *(const short8*)&Plds[w][lr][lq * 8];

    // PV: 32 channel tiles
#pragma unroll
    for (int ct = 0; ct < 32; ++ct) {
      short8 vf = *(const short8*)&Vlds[ct * 16 + lr][lq * 8];
      acc[ct] = __builtin_amdgcn_mfma_f32_16x16x32_bf16(pf, vf, acc[ct], 0, 0, 0);
    }
    __syncthreads();
  }

  // epilogue: out[b][c][n] = gamma * O/L + x, transposed via LDS for coalescing
  float invL[4];
#pragma unroll
  for (int r = 0; r < 4; ++r) invL[r] = 1.f / L[r];
  const float g = gamma[0];
  float* Ol = (float*)&Vlds[0][0];            // reuse: [128][68] f32 = 34.8KB
  const int rr = t >> 4, nn = (t & 15) * 4;

#pragma unroll
  for (int cb = 0; cb < 4; ++cb) {
    __syncthreads();
#pragma unroll
    for (int ct = 0; ct < 8; ++ct) {
      const int cti = cb * 8 + ct;
#pragma unroll
      for (int r = 0; r < 4; ++r)
        Ol[(ct * 16 + lr) * 68 + w * 16 + lq * 4 + r] = acc[cti][r] * invL[r];
    }
    __syncthreads();
#pragma unroll
    for (int p = 0; p < 8; ++p) {
      const int row = p * 16 + rr;
      const int c = cb * 128 + row;
      const size_t go = ((size_t)b * CCH + c) * NPIX + q0 + nn;
      float4 xv = *(const float4*)&x[go];
      float4 ov = *(const float4*)&Ol[row * 68 + nn];
      float4 res;
      res.x = g * ov.x + xv.x; res.y = g * ov.y + xv.y;
      res.z = g * ov.z + xv.z; res.w = g * ov.w + xv.w;
      *(float4*)&out[go] = res;
    }
  }
}

extern "C" void kernel_launch(void* const* d_in, const int* in_sizes, int n_in,
                              void* d_out, int out_size, void* d_ws, size_t ws_size,
                              hipStream_t stream) {
  const float* x     = (const float*)d_in[0];
  const float* wq    = (const float*)d_in[1];
  const float* bq    = (const float*)d_in[2];
  const float* wk    = (const float*)d_in[3];
  const float* bk    = (const float*)d_in[4];
  const float* wv    = (const float*)d_in[5];
  const float* bv    = (const float*)d_in[6];
  const float* gamma = (const float*)d_in[7];
  float* out = (float*)d_out;

  // Xt (32MB bf16) lives in d_out (64MB) — dead before k_attn writes the output.
  ushort* Xt = (ushort*)d_out;
  ushort* Wb = (ushort*)d_ws;                          // 640*512
  ushort* Qb = Wb + (size_t)640 * 512;                 // 8*4096*64
  ushort* Kb = Qb + (size_t)8 * NPIX * DQK;            // 8*4096*64
  ushort* Vb = Kb + (size_t)8 * NPIX * DQK;            // 8*512*4096
  // total ws: ~42.6 MB

  k_cast_x<<<dim3(NPIX / 32, CCH / 32, 8), 256, 0, stream>>>(x, Xt);
  k_cast_w<<<(640 * 512 / 4) / 256, 256, 0, stream>>>(wq, wk, wv, Wb);
  k_proj<<<dim3(NPIX / 64, 640 / 64, 8), 256, 0, stream>>>(Xt, Wb, bq, bk, bv, Qb, Kb, Vb);
  k_attn<<<dim3(NPIX / 64, 8), 256, 0, stream>>>(Qb, Kb, Vb, x, gamma, out);
}

// Round 2
// 531.522 us; speedup vs baseline: 1.2440x; 1.2440x over previous
//
#include <hip/hip_runtime.h>

typedef float  f32x4  __attribute__((ext_vector_type(4)));
typedef float  f32x16 __attribute__((ext_vector_type(16)));
typedef short  short8 __attribute__((ext_vector_type(8)));
typedef unsigned int uint4v __attribute__((ext_vector_type(4)));

#define LOG2E 1.4426950408889634f
#define NPIX 4096
#define CCH  512
#define DQK  64

__device__ __forceinline__ ushort f2b(float f) {
  union { float f; unsigned u; } v; v.f = f;
  unsigned r = v.u + 0x7fffu + ((v.u >> 16) & 1u);
  return (ushort)(r >> 16);
}

__device__ __forceinline__ unsigned cvt_pk_bf16(float lo, float hi) {
  unsigned r;
  asm("v_cvt_pk_bf16_f32 %0, %1, %2" : "=v"(r) : "v"(lo), "v"(hi));
  return r;
}

// x: [B][C][N] f32  ->  Xt: [B][N][C] bf16  (tiled transpose via LDS)
__global__ __launch_bounds__(256) void k_cast_x(const float* __restrict__ x,
                                                ushort* __restrict__ Xt) {
  __shared__ float tile[32][33];
  const int b = blockIdx.z;
  const int n0 = blockIdx.x * 32, c0 = blockIdx.y * 32;
  const int t = threadIdx.x;
  {
    int cc = t >> 3, nn = (t & 7) * 4;
    const float4 v = *(const float4*)&x[((size_t)b * CCH + c0 + cc) * NPIX + n0 + nn];
    tile[cc][nn] = v.x; tile[cc][nn + 1] = v.y; tile[cc][nn + 2] = v.z; tile[cc][nn + 3] = v.w;
  }
  __syncthreads();
  {
    int nr = t >> 3, c4 = (t & 7) * 4;
    ushort4 o;
    o.x = f2b(tile[c4 + 0][nr]); o.y = f2b(tile[c4 + 1][nr]);
    o.z = f2b(tile[c4 + 2][nr]); o.w = f2b(tile[c4 + 3][nr]);
    *(ushort4*)&Xt[((size_t)b * NPIX + n0 + nr) * CCH + c0 + c4] = o;
  }
}

// pack wq(64x512), wk(64x512), wv(512x512) -> Wb[640][512] bf16
__global__ __launch_bounds__(256) void k_cast_w(const float* __restrict__ wq,
                                                const float* __restrict__ wk,
                                                const float* __restrict__ wv,
                                                ushort* __restrict__ Wb) {
  int i = blockIdx.x * 256 + threadIdx.x;
  int idx = i * 4;
  int j = idx >> 9, c = idx & 511;
  const float* src = (j < 64) ? &wq[(size_t)j * 512]
                   : (j < 128) ? &wk[(size_t)(j - 64) * 512]
                               : &wv[(size_t)(j - 128) * 512];
  float4 v = *(const float4*)&src[c];
  ushort4 o; o.x = f2b(v.x); o.y = f2b(v.y); o.z = f2b(v.z); o.w = f2b(v.w);
  *(ushort4*)&Wb[idx] = o;
}

// QKV projection GEMM: out[j,n] = sum_c Wb[j,c]*Xt[n,c] + bias[j]
// Q: [B][N][64], K: [B][N][64], V: [B][C][N]  (all bf16)
__global__ __launch_bounds__(256) void k_proj(const ushort* __restrict__ Xt,
                                              const ushort* __restrict__ Wb,
                                              const float* __restrict__ bq,
                                              const float* __restrict__ bk,
                                              const float* __restrict__ bv,
                                              ushort* __restrict__ Q,
                                              ushort* __restrict__ K,
                                              ushort* __restrict__ V) {
  __shared__ ushort Wl[64][72];
  __shared__ ushort Xl[64][72];
  const int b = blockIdx.z;
  const int n0 = blockIdx.x * 64;
  const int j0 = blockIdx.y * 64;
  const int t = threadIdx.x;
  const int w = t >> 6, l = t & 63;
  const int lr = l & 15, lq = l >> 4;
  const int wj = (w >> 1) * 32, wn = (w & 1) * 32;

  f32x4 acc[2][2];
#pragma unroll
  for (int a = 0; a < 2; ++a)
#pragma unroll
    for (int c = 0; c < 2; ++c) acc[a][c] = f32x4{0.f, 0.f, 0.f, 0.f};

  const int srow = t >> 2, sch = t & 3;
  for (int k0 = 0; k0 < 512; k0 += 64) {
    *(uint4*)&Wl[srow][sch * 8]       = *(const uint4*)&Wb[(size_t)(j0 + srow) * 512 + k0 + sch * 8];
    *(uint4*)&Wl[srow][(sch + 4) * 8] = *(const uint4*)&Wb[(size_t)(j0 + srow) * 512 + k0 + (sch + 4) * 8];
    *(uint4*)&Xl[srow][sch * 8]       = *(const uint4*)&Xt[((size_t)b * NPIX + n0 + srow) * 512 + k0 + sch * 8];
    *(uint4*)&Xl[srow][(sch + 4) * 8] = *(const uint4*)&Xt[((size_t)b * NPIX + n0 + srow) * 512 + k0 + (sch + 4) * 8];
    __syncthreads();
#pragma unroll
    for (int kt = 0; kt < 2; ++kt) {
      short8 af[2], bf[2];
#pragma unroll
      for (int jt = 0; jt < 2; ++jt)
        af[jt] = *(const short8*)&Wl[wj + jt * 16 + lr][kt * 32 + lq * 8];
#pragma unroll
      for (int nt = 0; nt < 2; ++nt)
        bf[nt] = *(const short8*)&Xl[wn + nt * 16 + lr][kt * 32 + lq * 8];
#pragma unroll
      for (int jt = 0; jt < 2; ++jt)
#pragma unroll
        for (int nt = 0; nt < 2; ++nt)
          acc[jt][nt] = __builtin_amdgcn_mfma_f32_16x16x32_bf16(af[jt], bf[nt], acc[jt][nt], 0, 0, 0);
    }
    __syncthreads();
  }

#pragma unroll
  for (int jt = 0; jt < 2; ++jt) {
    const int jb = j0 + wj + jt * 16;
#pragma unroll
    for (int nt = 0; nt < 2; ++nt) {
      const int n = n0 + wn + nt * 16 + lr;
      const size_t nrow = (size_t)b * NPIX + n;
      if (jb < 64) {
        ushort4 o;
        o.x = f2b(acc[jt][nt][0] + bq[jb + lq * 4 + 0]);
        o.y = f2b(acc[jt][nt][1] + bq[jb + lq * 4 + 1]);
        o.z = f2b(acc[jt][nt][2] + bq[jb + lq * 4 + 2]);
        o.w = f2b(acc[jt][nt][3] + bq[jb + lq * 4 + 3]);
        *(ushort4*)&Q[nrow * DQK + jb + lq * 4] = o;
      } else if (jb < 128) {
        ushort4 o;
        o.x = f2b(acc[jt][nt][0] + bk[jb - 64 + lq * 4 + 0]);
        o.y = f2b(acc[jt][nt][1] + bk[jb - 64 + lq * 4 + 1]);
        o.z = f2b(acc[jt][nt][2] + bk[jb - 64 + lq * 4 + 2]);
        o.w = f2b(acc[jt][nt][3] + bk[jb - 64 + lq * 4 + 3]);
        *(ushort4*)&K[nrow * DQK + jb - 64 + lq * 4] = o;
      } else {
#pragma unroll
        for (int r = 0; r < 4; ++r) {
          int cch = jb - 128 + lq * 4 + r;
          V[((size_t)b * CCH + cch) * NPIX + n] = f2b(acc[jt][nt][r] + bv[cch]);
        }
      }
    }
  }
}

// flash attention, 32x32x16 MFMA, no LDS / no barriers.
// 512 threads = 8 waves = 2 q-pairs (64q each) x 4 c-groups (128c each).
// Per wave: S^T = K*Q^T (lane = query col), in-register softmax + cvt_pk/half-swap
// to build P^T B-fragments, PV as O^T = V^T * P^T.
__global__ __launch_bounds__(512, 2) void k_attn(const ushort* __restrict__ Qb,
                                                 const ushort* __restrict__ Kb,
                                                 const ushort* __restrict__ Vb,
                                                 const float* __restrict__ x,
                                                 const float* __restrict__ gamma,
                                                 float* __restrict__ out) {
  const int b = blockIdx.y;
  const int t = threadIdx.x;
  const int w = t >> 6, l = t & 63;
  const int lq = l & 31, h = l >> 5;
  const int q0 = blockIdx.x * 128 + (w >> 2) * 64;   // wave's 64-query base
  const int c0 = (w & 3) * 128;                      // wave's 128-channel base

  // Q fragments (B-operand): lane holds Q[q0+qt*32+lq][ks*16 + h*8 .. +7]
  short8 qf[2][4];
#pragma unroll
  for (int qt = 0; qt < 2; ++qt)
#pragma unroll
    for (int ks = 0; ks < 4; ++ks)
      qf[qt][ks] = *(const short8*)&Qb[((size_t)b * NPIX + q0 + qt * 32 + lq) * DQK + ks * 16 + h * 8];

  f32x16 acc[2][4] = {};
  float M[2] = {-1e30f, -1e30f}, L[2] = {0.f, 0.f};

  const size_t kbase = (size_t)b * NPIX * DQK;
  const size_t vbase = ((size_t)b * CCH + c0) * NPIX;

  for (int m0 = 0; m0 < NPIX; m0 += 64) {
#pragma unroll
    for (int rd = 0; rd < 2; ++rd) {
      const int key0 = m0 + rd * 32;

      // V fragments (A-operand for PV): lane holds V[c0+ct*32+lq][key0 + kt*16 + h*8 ..]
      short8 vf[4][2];
#pragma unroll
      for (int ct = 0; ct < 4; ++ct)
#pragma unroll
        for (int kt = 0; kt < 2; ++kt)
          vf[ct][kt] = *(const short8*)&Vb[vbase + (size_t)(ct * 32 + lq) * NPIX + key0 + kt * 16 + h * 8];

      // S^T = K * Q^T : rows = keys, cols = queries (lane's own query = lq)
      f32x16 s[2] = {};
#pragma unroll
      for (int ks = 0; ks < 4; ++ks) {
        short8 kf = *(const short8*)&Kb[kbase + (size_t)(key0 + lq) * DQK + ks * 16 + h * 8];
        s[0] = __builtin_amdgcn_mfma_f32_32x32x16_bf16(kf, qf[0][ks], s[0], 0, 0, 0);
        s[1] = __builtin_amdgcn_mfma_f32_32x32x16_bf16(kf, qf[1][ks], s[1], 0, 0, 0);
      }

      // row max per qtile (16 regs + cross-half swap)
      float rm[2];
#pragma unroll
      for (int qt = 0; qt < 2; ++qt) {
        float a0 = fmaxf(s[qt][0],  s[qt][1]),  a1 = fmaxf(s[qt][2],  s[qt][3]);
        float a2 = fmaxf(s[qt][4],  s[qt][5]),  a3 = fmaxf(s[qt][6],  s[qt][7]);
        float a4 = fmaxf(s[qt][8],  s[qt][9]),  a5 = fmaxf(s[qt][10], s[qt][11]);
        float a6 = fmaxf(s[qt][12], s[qt][13]), a7 = fmaxf(s[qt][14], s[qt][15]);
        float m01 = fmaxf(fmaxf(a0, a1), fmaxf(a2, a3));
        float m23 = fmaxf(fmaxf(a4, a5), fmaxf(a6, a7));
        float mm = fmaxf(m01, m23);
        rm[qt] = fmaxf(mm, __shfl_xor(mm, 32));
      }

      // defer-max (T13): only rescale when max grew past threshold
      bool need = (rm[0] > M[0] + 8.f) || (rm[1] > M[1] + 8.f);
      if (__any((int)need)) {
#pragma unroll
        for (int qt = 0; qt < 2; ++qt) {
          float nm = fmaxf(M[qt], rm[qt]);
          float sc = exp2f((M[qt] - nm) * LOG2E);
          L[qt] *= sc; M[qt] = nm;
#pragma unroll
          for (int ct = 0; ct < 4; ++ct)
#pragma unroll
            for (int r = 0; r < 16; ++r) acc[qt][ct][r] *= sc;
        }
      }

      // P = exp(S - M), packed to bf16 pairs; L += rowsum
      uint pk[2][8];
#pragma unroll
      for (int qt = 0; qt < 2; ++qt) {
        const float mM = M[qt] * LOG2E;
        float sum = 0.f;
#pragma unroll
        for (int j = 0; j < 8; ++j) {
          float p0 = exp2f(fmaf(s[qt][2 * j],     LOG2E, -mM));
          float p1 = exp2f(fmaf(s[qt][2 * j + 1], LOG2E, -mM));
          sum += p0 + p1;
          pk[qt][j] = cvt_pk_bf16(p0, p1);
        }
        sum += __shfl_xor(sum, 32);
        L[qt] += sum;
      }

      // assemble P^T B-fragments (half-swap) and PV: O^T += V^T * P^T
#pragma unroll
      for (int qt = 0; qt < 2; ++qt) {
        uint sw[8];
#pragma unroll
        for (int j = 0; j < 8; ++j) sw[j] = __shfl_xor(pk[qt][j], 32);
        union { uint4v u; short8 s8; } B0, B1;
        B0.u[0] = h ? sw[2]     : pk[qt][0];
        B0.u[1] = h ? sw[3]     : pk[qt][1];
        B0.u[2] = h ? pk[qt][2] : sw[0];
        B0.u[3] = h ? pk[qt][3] : sw[1];
        B1.u[0] = h ? sw[6]     : pk[qt][4];
        B1.u[1] = h ? sw[7]     : pk[qt][5];
        B1.u[2] = h ? pk[qt][6] : sw[4];
        B1.u[3] = h ? pk[qt][7] : sw[5];
#pragma unroll
        for (int ct = 0; ct < 4; ++ct) {
          acc[qt][ct] = __builtin_amdgcn_mfma_f32_32x32x16_bf16(vf[ct][0], B0.s8, acc[qt][ct], 0, 0, 0);
          acc[qt][ct] = __builtin_amdgcn_mfma_f32_32x32x16_bf16(vf[ct][1], B1.s8, acc[qt][ct], 0, 0, 0);
        }
      }
    }
  }

  // epilogue: out[b][c][n] = gamma * O/L + x  (col = query -> contiguous stores)
  const float g = gamma[0];
  float gi[2] = {g / L[0], g / L[1]};
#pragma unroll
  for (int qt = 0; qt < 2; ++qt)
#pragma unroll
    for (int ct = 0; ct < 4; ++ct)
#pragma unroll
      for (int r = 0; r < 16; ++r) {
        int c = c0 + ct * 32 + (r & 3) + 8 * (r >> 2) + 4 * h;
        size_t off = ((size_t)b * CCH + c) * NPIX + q0 + qt * 32 + lq;
        out[off] = gi[qt] * acc[qt][ct][r] + x[off];
      }
}

extern "C" void kernel_launch(void* const* d_in, const int* in_sizes, int n_in,
                              void* d_out, int out_size, void* d_ws, size_t ws_size,
                              hipStream_t stream) {
  const float* x     = (const float*)d_in[0];
  const float* wq    = (const float*)d_in[1];
  const float* bq    = (const float*)d_in[2];
  const float* wk    = (const float*)d_in[3];
  const float* bk    = (const float*)d_in[4];
  const float* wv    = (const float*)d_in[5];
  const float* bv    = (const float*)d_in[6];
  const float* gamma = (const float*)d_in[7];
  float* out = (float*)d_out;

  // Xt (32MB bf16) lives in d_out (64MB) — dead before k_attn writes the output.
  ushort* Xt = (ushort*)d_out;
  ushort* Wb = (ushort*)d_ws;                          // 640*512
  ushort* Qb = Wb + (size_t)640 * 512;                 // 8*4096*64
  ushort* Kb = Qb + (size_t)8 * NPIX * DQK;            // 8*4096*64
  ushort* Vb = Kb + (size_t)8 * NPIX * DQK;            // 8*512*4096
  // total ws: ~42.6 MB

  k_cast_x<<<dim3(NPIX / 32, CCH / 32, 8), 256, 0, stream>>>(x, Xt);
  k_cast_w<<<(640 * 512 / 4) / 256, 256, 0, stream>>>(wq, wk, wv, Wb);
  k_proj<<<dim3(NPIX / 64, 640 / 64, 8), 256, 0, stream>>>(Xt, Wb, bq, bk, bv, Qb, Kb, Vb);
  k_attn<<<dim3(NPIX / 128, 8), 512, 0, stream>>>(Qb, Kb, Vb, x, gamma, out);
}